// Round 11
// baseline (403.373 us; speedup 1.0000x reference)
//
#include <hip/hip_runtime.h>
#include <math.h>

#define NPOLES 80
#define NP 161          // 2*NPOLES+1
#define NPAD 164
#define TSEQ 36
#define NSAMP 128
#define DDATA 50
#define LAMF 0.1f
#define NPD (NP*DDATA)      // 8050
#define TD (TSEQ*DDATA)     // 1800
#define CSIZE (NSAMP*NPD)   // 1030400
#define RSIZE (NSAMP*TD)    // 230400
#define DSIZE (TSEQ*NP)     // 5796

#define RT_N 11             // 176 padded rows / 16
#define KC_N 5              // k chunks of 32 (q=0..159); q=160 via rank-1
#define FRAG_CHUNK 512      // shorts per (rt,kc) fragment: 64 lanes * 8

// y LDS layout: byte = slot*256 + hl*128 + c0*8 ; slot=row/4 (0..39), dbuf stride 10240B
#define YBUF 10240

typedef __attribute__((ext_vector_type(8))) short s8b;
typedef __attribute__((ext_vector_type(4))) float f4;

struct u2x2 { uint2 a, b; };

__device__ __forceinline__ unsigned short f2b(float f) {
    unsigned u = __float_as_uint(f);
    unsigned r = (u + 0x7FFFu + ((u >> 16) & 1u)) >> 16;   // RNE to bf16
    return (unsigned short)r;
}
__device__ __forceinline__ float b2f(unsigned short h) {
    return __uint_as_float(((unsigned)h) << 16);
}

// ---------------- D matrix (clamped poles) ----------------------------------
__global__ void k_build_D(const float* __restrict__ rho, const float* __restrict__ theta,
                          float* __restrict__ Dw, float* __restrict__ Dout) {
    int idx = blockIdx.x * 256 + threadIdx.x;
    if (idx >= DSIZE) return;
    int t = idx / NP, p = idx - (idx / NP) * NP;
    float v;
    if (p == 0) {
        v = 1.f;
    } else {
        int j = (p <= NPOLES) ? (p - 1) : (p - 1 - NPOLES);
        float r  = fminf(fmaxf(rho[j],   0.8f), 1.1f);
        float th = fminf(fmaxf(theta[j], 0.1f), 3.14159265358979323846f);
        double pw  = pow((double)r, (double)t);
        double ang = (double)t * (double)th;
        v = (float)(pw * ((p <= NPOLES) ? cos(ang) : sin(ang)));
    }
    Dw[idx] = v;
    Dout[idx] = v;
}

// ---- L estimator: fused DDt + 8 matrix squarings + Rayleigh (1 block) ------
__global__ __launch_bounds__(256) void k_power2(const float* __restrict__ Dw,
                                                float* __restrict__ scal,
                                                float* __restrict__ ttab) {
    __shared__ float sM[1296];
    __shared__ float sB0[1296];
    __shared__ float sB1[1296];
    __shared__ float sred[256];
    __shared__ float sv[40];
    const int tid = threadIdx.x;

    // momentum table (identical float ops to prior rounds)
    if (tid == 0) {
        float t = 1.f;
        for (int k = 0; k < 100; ++k) {
            float tn = (1.f + sqrtf(fmaf(4.f * t, t, 1.f))) * 0.5f;
            ttab[k] = (t - 1.f) / tn;
            t = tn;
        }
    }

    // DDt = D @ D^T (same p-ascending fma order as the old k_ddt -> same bits)
    for (int idx = tid; idx < 1296; idx += 256) {
        int i = idx / 36, j = idx - (idx / 36) * 36;
        float acc = 0.f;
        for (int p = 0; p < NP; ++p) acc = fmaf(Dw[i * NP + p], Dw[j * NP + p], acc);
        sM[idx] = acc;
    }
    __syncthreads();

    // normalize by max|.|
    {
        float mx = 0.f;
        for (int idx = tid; idx < 1296; idx += 256) mx = fmaxf(mx, fabsf(sM[idx]));
        sred[tid] = mx;
        __syncthreads();
        for (int s = 128; s > 0; s >>= 1) {
            if (tid < s) sred[tid] = fmaxf(sred[tid], sred[tid + s]);
            __syncthreads();
        }
        float inv = 1.f / sred[0];
        for (int idx = tid; idx < 1296; idx += 256) sB0[idx] = sM[idx] * inv;
    }
    __syncthreads();

    // 8 matrix squarings (M^256 direction), max-normalized each step
    float* bs = sB0;
    float* bd = sB1;
    for (int sq = 0; sq < 8; ++sq) {
        for (int idx = tid; idx < 1296; idx += 256) {
            int i = idx / 36, j = idx - (idx / 36) * 36;
            float acc = 0.f;
            for (int k2 = 0; k2 < 36; ++k2) acc = fmaf(bs[i * 36 + k2], bs[k2 * 36 + j], acc);
            bd[idx] = acc;
        }
        __syncthreads();
        float m2 = 0.f;
        for (int idx = tid; idx < 1296; idx += 256) m2 = fmaxf(m2, fabsf(bd[idx]));
        sred[tid] = m2;
        __syncthreads();
        for (int s = 128; s > 0; s >>= 1) {
            if (tid < s) sred[tid] = fmaxf(sred[tid], sred[tid + s]);
            __syncthreads();
        }
        float inv = 1.f / sred[0];
        for (int idx = tid; idx < 1296; idx += 256) bd[idx] *= inv;
        __syncthreads();
        float* tmp = bs; bs = bd; bd = tmp;
    }

    // v = B·ones; Rayleigh quotient on original M -> L
    if (tid < 36) {
        float s = 0.f;
        for (int k2 = 0; k2 < 36; ++k2) s += bs[tid * 36 + k2];
        sv[tid] = s;
    }
    __syncthreads();
    if (tid < 36) {
        float u = 0.f;
        for (int k2 = 0; k2 < 36; ++k2) u = fmaf(sM[tid * 36 + k2], sv[k2], u);
        sred[tid] = u * sv[tid];
        sred[40 + tid] = sv[tid] * sv[tid];
    }
    __syncthreads();
    if (tid == 0) {
        float num = 0.f, den = 0.f;
        for (int i = 0; i < 36; ++i) { num += sred[i]; den += sred[40 + i]; }
        float L = num / den;
        scal[0] = 1.f / L; scal[1] = L;
    }
}

// ---------------- A = I - DtD/L, padded symmetric [q][p] --------------------
__global__ void k_A(const float* __restrict__ Dw, const float* __restrict__ scal,
                    float* __restrict__ Apad) {
    int idx = blockIdx.x * 256 + threadIdx.x;
    if (idx >= NP * NPAD) return;
    int q = idx / NPAD, p = idx - (idx / NPAD) * NPAD;
    float v = 0.f;
    if (p < NP) {
        float acc = 0.f;
        for (int t = 0; t < TSEQ; ++t) acc = fmaf(Dw[t * NP + q], Dw[t * NP + p], acc);
        v = ((p == q) ? 1.f : 0.f) - acc * scal[0];
    }
    Apad[idx] = v;
}

// -------- DtY[n,p,d], Y[n] staged in LDS (bit-identical t-ascending fma) ----
__global__ __launch_bounds__(256) void k_dty(const float* __restrict__ Dw,
                                             const float* __restrict__ Y,
                                             float* __restrict__ dty) {
    __shared__ float sY[TD];               // 7200 B
    const int tid = threadIdx.x;
    const int n = blockIdx.x;
    for (int i = tid; i < TD; i += 256) sY[i] = Y[n * TD + i];
    __syncthreads();
    for (int o = tid; o < NPD; o += 256) {
        int p = o / DDATA, d = o - (o / DDATA) * DDATA;
        float acc = 0.f;
        for (int t = 0; t < TSEQ; ++t)
            acc = fmaf(Dw[t * NP + p], sY[t * DDATA + d], acc);
        dty[n * NPD + o] = acc;
    }
}

// ---------------- pack A into MFMA fragment order, split bf16 hi/lo ---------
__global__ void k_Afrag(const float* __restrict__ Apad,
                        short* __restrict__ AfH, short* __restrict__ AfL) {
    int idx = blockIdx.x * 256 + threadIdx.x;
    if (idx >= RT_N * KC_N * 64) return;
    int lane = idx & 63;
    int chunk = idx >> 6;
    int kc = chunk % KC_N;
    int rt = chunk / KC_N;
    int p = rt * 16 + (lane & 15);
    int q0 = kc * 32 + (lane >> 4) * 8;
    int base = chunk * FRAG_CHUNK + lane * 8;
#pragma unroll
    for (int j = 0; j < 8; ++j) {
        int q = q0 + j;
        float v = (p < NP && q < NP) ? Apad[q * NPAD + p] : 0.f;  // A[p][q] (symmetric)
        unsigned short h = f2b(v);
        float rem = v - b2f(h);
        AfH[base + j] = (short)h;
        AfL[base + j] = (short)f2b(rem);
    }
}

// ---------------- persistent MFMA FISTA: A in regs, conflict-free y LDS -----
// block=(n, col-quarter dq: 13,13,13,11 cols). grid 512 -> 2 blocks/CU.
// 4 waves: wave w owns row-tiles rt0=w*3 (3,3,3,2), one 16-col tile.
__global__ __launch_bounds__(256, 2) void k_fista(
    const float* __restrict__ Apad,
    const s8b* __restrict__ AfH, const s8b* __restrict__ AfL,
    const float* __restrict__ dty_g, const float* __restrict__ scal,
    const float* __restrict__ ttab, float* __restrict__ Cout)
{
    __shared__ char Yb[2 * YBUF];      // slot*256 + hl*128 + c0*8 (+cur*YBUF)
    __shared__ float yremf[2][16];     // y[row 160][col] f32
    __shared__ float colpart[4][16];
    __shared__ float sS[16];

    const int tid = threadIdx.x;
    const int n  = blockIdx.x >> 2;
    const int dq = blockIdx.x & 3;
    const int w = tid >> 6;
    const int lane = tid & 63;
    const int c0 = lane & 15;
    const int g = lane >> 4;
    const int rt0 = w * 3;
    const int ntr = (w == 3) ? 2 : 3;
    const int ncol = (dq == 3) ? 11 : 13;
    const int colv = dq * 13 + c0;
    const bool cvalid = c0 < ncol;
    const float Linv = scal[0];
    const float lamL = LAMF * Linv;

    const int rdbase = (c0 << 3) + (g << 9);   // c0*8 + g*512
    const int wrbase = (c0 << 3);              // + slot*256 (+128 for lo)

    // ---- persistent A fragments in registers (one-time coalesced load) ----
    s8b ahr[3][KC_N], alr[3][KC_N];
    const s8b zer = {0, 0, 0, 0, 0, 0, 0, 0};
#pragma unroll
    for (int rr = 0; rr < 3; ++rr) {
#pragma unroll
        for (int kc = 0; kc < KC_N; ++kc) {
            if (rr < ntr) {
                int ck = (rt0 + rr) * KC_N + kc;
                ahr[rr][kc] = AfH[ck * 64 + lane];
                alr[rr][kc] = AfL[ck * 64 + lane];
            } else {
                ahr[rr][kc] = zer;
                alr[rr][kc] = zer;
            }
        }
    }

    // tile geometry + dty*Linv + A[:,160] rows (C/D layout: col=l&15, row=g*4+reg)
    int rowb[3];
    float dtL[3][4];
    f4 a160r[3];
#pragma unroll
    for (int rr = 0; rr < 3; ++rr) {
        rowb[rr] = (rt0 + rr) * 16 + g * 4;
#pragma unroll
        for (int r = 0; r < 4; ++r) {
            int row = rowb[rr] + r;
            float v = 0.f;
            if ((rr < ntr) && row < NP && cvalid)
                v = dty_g[n * NPD + row * DDATA + colv];
            dtL[rr][r] = v * Linv;
            a160r[rr][r] = ((rr < ntr) && row < NP) ? Apad[160 * NPAD + row] : 0.f;
        }
    }

    float x_[3][4], wlam_[3][4];
#pragma unroll
    for (int rr = 0; rr < 3; ++rr)
#pragma unroll
        for (int r = 0; r < 4; ++r) wlam_[rr][r] = lamL;

#pragma unroll 1
    for (int round = 0; round < 2; ++round) {
#pragma unroll
        for (int rr = 0; rr < 3; ++rr)
#pragma unroll
            for (int r = 0; r < 4; ++r) x_[rr][r] = 0.f;
        {   // zero read-buffer (index 0); write-buffer fully overwritten at it 0
            unsigned* pz = (unsigned*)Yb;
            for (int i = tid; i < YBUF / 4; i += 256) pz[i] = 0u;
            if (tid < 16) yremf[0][tid] = 0.f;
        }
        int cur = 0;
        __syncthreads();

#pragma unroll 1
        for (int it = 0; it < 100; ++it) {
            const float ttc = ttab[it];          // uniform -> scalar load
            const int nxt = cur ^ 1;
            const char* rp = Yb + cur * YBUF + rdbase;
            char* wp = Yb + nxt * YBUF + wrbase;

            // accumulator initialized with DtY*Linv (folds the bb add)
            f4 acc[3];
#pragma unroll
            for (int rr = 0; rr < 3; ++rr)
#pragma unroll
                for (int r = 0; r < 4; ++r) acc[rr][r] = dtL[rr][r];

            __builtin_amdgcn_s_setprio(1);
#pragma unroll
            for (int kc = 0; kc < KC_N; ++kc) {
                const char* p = rp + kc * 2048;
                u2x2 hh2, ll2;
                hh2.a = *(const uint2*)(p);
                hh2.b = *(const uint2*)(p + 256);
                ll2.a = *(const uint2*)(p + 128);
                ll2.b = *(const uint2*)(p + 384);
                s8b bh = __builtin_bit_cast(s8b, hh2);
                s8b bl = __builtin_bit_cast(s8b, ll2);
#pragma unroll
                for (int rr = 0; rr < 3; ++rr) {
                    if (rr < ntr) {
                        acc[rr] = __builtin_amdgcn_mfma_f32_16x16x32_bf16(ahr[rr][kc], bh, acc[rr], 0, 0, 0);
                        acc[rr] = __builtin_amdgcn_mfma_f32_16x16x32_bf16(ahr[rr][kc], bl, acc[rr], 0, 0, 0);
                        acc[rr] = __builtin_amdgcn_mfma_f32_16x16x32_bf16(alr[rr][kc], bh, acc[rr], 0, 0, 0);
                    }
                }
            }
            {   // q=160 rank-1 term in f32
                float yv = yremf[cur][c0];
#pragma unroll
                for (int rr = 0; rr < 3; ++rr)
                    if (rr < ntr)
#pragma unroll
                        for (int r = 0; r < 4; ++r)
                            acc[rr][r] = fmaf(a160r[rr][r], yv, acc[rr][r]);
            }
            __builtin_amdgcn_s_setprio(0);

            // epilogue: clamp soft-threshold + momentum + truncation-split y
#pragma unroll
            for (int rr = 0; rr < 3; ++rr) {
                if (rr < ntr) {
                    unsigned yb4[4], rb4[4];
                    float yn0 = 0.f;
#pragma unroll
                    for (int r = 0; r < 4; ++r) {
                        float bb = acc[rr][r];
                        float wl = wlam_[rr][r];
                        float cl = fminf(fmaxf(bb, -wl), wl);   // med3 clamp
                        float xn = bb - cl;                      // soft-threshold
                        float yn = fmaf(ttc, xn - x_[rr][r], xn);
                        x_[rr][r] = xn;
                        if (r == 0) yn0 = yn;
                        unsigned u = __float_as_uint(yn);
                        yb4[r] = u;
                        rb4[r] = __float_as_uint(yn - __uint_as_float(u & 0xFFFF0000u));
                    }
                    int rt = rt0 + rr;
                    if (rt < 10) {
                        uint2 hp, lp;
                        hp.x = __builtin_amdgcn_perm(yb4[1], yb4[0], 0x07060302u);
                        hp.y = __builtin_amdgcn_perm(yb4[3], yb4[2], 0x07060302u);
                        lp.x = __builtin_amdgcn_perm(rb4[1], rb4[0], 0x07060302u);
                        lp.y = __builtin_amdgcn_perm(rb4[3], rb4[2], 0x07060302u);
                        char* q = wp + (rt * 4 + g) * 256;
                        *(uint2*)(q)       = hp;
                        *(uint2*)(q + 128) = lp;
                    } else if (g == 0) {
                        yremf[nxt][c0] = yn0;   // row 160 (rows >160 are pad, y=0)
                    }
                }
            }
            __syncthreads();   // writes to nxt visible; all reads of cur complete
            cur = nxt;
        }

        if (round == 0) {
            // reweight: wlam = (1/(|x|+.01)) / colsum(1/(|x|+.01)) * NP * lamL
            float ps = 0.f;
#pragma unroll
            for (int rr = 0; rr < 3; ++rr) {
                if (rr < ntr) {
#pragma unroll
                    for (int r = 0; r < 4; ++r) {
                        if (rowb[rr] + r < NP)
                            ps += 1.f / (fabsf(x_[rr][r]) + 0.01f);
                    }
                }
            }
            ps += __shfl_xor(ps, 16);
            ps += __shfl_xor(ps, 32);
            if (lane < 16) colpart[w][lane] = ps;
            __syncthreads();
            if (tid < 16) {
                float s = colpart[0][tid] + colpart[1][tid] + colpart[2][tid] + colpart[3][tid];
                sS[tid] = (float)NP / s;
            }
            __syncthreads();
            float sc = sS[c0] * lamL;
#pragma unroll
            for (int rr = 0; rr < 3; ++rr)
#pragma unroll
                for (int r = 0; r < 4; ++r)
                    wlam_[rr][r] = (1.f / (fabsf(x_[rr][r]) + 0.01f)) * sc;
            __syncthreads();
        }
    }

    // store C (f32)
#pragma unroll
    for (int rr = 0; rr < 3; ++rr) {
        if ((rr < ntr) && cvalid) {
#pragma unroll
            for (int r = 0; r < 4; ++r) {
                int row = rowb[rr] + r;
                if (row < NP)
                    Cout[n * NPD + row * DDATA + colv] = x_[rr][r];
            }
        }
    }
}

// -------- R = D @ C, C[n] staged in LDS (bit-identical p-ascending fma) -----
__global__ __launch_bounds__(256) void k_R(const float* __restrict__ Dw,
                                           const float* __restrict__ Cf,
                                           float* __restrict__ Rout) {
    __shared__ float sC[NPD];              // 32200 B
    const int tid = threadIdx.x;
    const int n = blockIdx.x;
    for (int i = tid; i < NPD; i += 256) sC[i] = Cf[n * NPD + i];
    __syncthreads();
    for (int o = tid; o < TD; o += 256) {
        int t = o / DDATA, d = o - (o / DDATA) * DDATA;
        float acc = 0.f;
        for (int p = 0; p < NP; ++p)
            acc = fmaf(Dw[t * NP + p], sC[p * DDATA + d], acc);
        Rout[n * TD + o] = acc;
    }
}

extern "C" void kernel_launch(void* const* d_in, const int* in_sizes, int n_in,
                              void* d_out, int out_size, void* d_ws, size_t ws_size,
                              hipStream_t stream) {
    const float* Y     = (const float*)d_in[0];
    const float* rho   = (const float*)d_in[1];
    const float* theta = (const float*)d_in[2];
    float* Cout = (float*)d_out;
    float* Dout = Cout + CSIZE;
    float* Rout = Dout + DSIZE;

    float* ws    = (float*)d_ws;
    float* Dw    = ws;                 // 5824
    float* Apad  = Dw + 5824;          // 26416
    float* scal  = Apad + 26416;       // 16
    float* ttabd = scal + 16;          // 112
    float* dty   = ttabd + 112;        // CSIZE
    float* AfH_f = dty + CSIZE;        // 14080 floats (= 28160 shorts)
    float* AfL_f = AfH_f + 14080;      // 14080 floats

    k_build_D<<<(DSIZE + 255) / 256, 256, 0, stream>>>(rho, theta, Dw, Dout);
    k_power2<<<1, 256, 0, stream>>>(Dw, scal, ttabd);
    k_A<<<(NP * NPAD + 255) / 256, 256, 0, stream>>>(Dw, scal, Apad);
    k_dty<<<NSAMP, 256, 0, stream>>>(Dw, Y, dty);
    k_Afrag<<<(RT_N * KC_N * 64 + 255) / 256, 256, 0, stream>>>(Apad, (short*)AfH_f, (short*)AfL_f);

    k_fista<<<NSAMP * 4, 256, 0, stream>>>(Apad, (const s8b*)AfH_f, (const s8b*)AfL_f,
                                           dty, scal, ttabd, Cout);

    k_R<<<NSAMP, 256, 0, stream>>>(Dw, Cout, Rout);
}

// Round 12
// 389.032 us; speedup vs baseline: 1.0369x; 1.0369x over previous
//
#include <hip/hip_runtime.h>
#include <math.h>

#define NPOLES 80
#define NP 161          // 2*NPOLES+1
#define NPAD 164
#define TSEQ 36
#define NSAMP 128
#define DDATA 50
#define LAMF 0.1f
#define NPD (NP*DDATA)      // 8050
#define TD (TSEQ*DDATA)     // 1800
#define CSIZE (NSAMP*NPD)   // 1030400
#define RSIZE (NSAMP*TD)    // 230400
#define DSIZE (TSEQ*NP)     // 5796

#define RT_N 11             // 176 padded rows / 16
#define KC_N 5              // k chunks of 32 (q=0..159); q=160 via rank-1
#define FRAG_CHUNK 512      // shorts per (rt,kc) fragment: 64 lanes * 8

// y LDS layout: byte = slot*256 + hl*128 + c0*8 ; slot=row/4 (0..39), dbuf stride 10240B
#define YBUF 10240

typedef __attribute__((ext_vector_type(8))) short s8b;
typedef __attribute__((ext_vector_type(4))) float f4;

struct u2x2 { uint2 a, b; };

__device__ __forceinline__ unsigned short f2b(float f) {
    unsigned u = __float_as_uint(f);
    unsigned r = (u + 0x7FFFu + ((u >> 16) & 1u)) >> 16;   // RNE to bf16
    return (unsigned short)r;
}
__device__ __forceinline__ float b2f(unsigned short h) {
    return __uint_as_float(((unsigned)h) << 16);
}

// ---------------- D matrix (clamped poles) ----------------------------------
__global__ void k_build_D(const float* __restrict__ rho, const float* __restrict__ theta,
                          float* __restrict__ Dw, float* __restrict__ Dout) {
    int idx = blockIdx.x * 256 + threadIdx.x;
    if (idx >= DSIZE) return;
    int t = idx / NP, p = idx - (idx / NP) * NP;
    float v;
    if (p == 0) {
        v = 1.f;
    } else {
        int j = (p <= NPOLES) ? (p - 1) : (p - 1 - NPOLES);
        float r  = fminf(fmaxf(rho[j],   0.8f), 1.1f);
        float th = fminf(fmaxf(theta[j], 0.1f), 3.14159265358979323846f);
        double pw  = pow((double)r, (double)t);
        double ang = (double)t * (double)th;
        v = (float)(pw * ((p <= NPOLES) ? cos(ang) : sin(ang)));
    }
    Dw[idx] = v;
    Dout[idx] = v;
}

// ---- L estimator: fused DDt + 8 matrix squarings + Rayleigh (1 block) ------
__global__ __launch_bounds__(256) void k_power2(const float* __restrict__ Dw,
                                                float* __restrict__ scal,
                                                float* __restrict__ ttab) {
    __shared__ float sM[1296];
    __shared__ float sB0[1296];
    __shared__ float sB1[1296];
    __shared__ float sred[256];
    __shared__ float sv[40];
    const int tid = threadIdx.x;

    // momentum table (identical float ops to prior rounds)
    if (tid == 0) {
        float t = 1.f;
        for (int k = 0; k < 100; ++k) {
            float tn = (1.f + sqrtf(fmaf(4.f * t, t, 1.f))) * 0.5f;
            ttab[k] = (t - 1.f) / tn;
            t = tn;
        }
    }

    // DDt = D @ D^T (same p-ascending fma order as the original k_ddt -> same bits)
    for (int idx = tid; idx < 1296; idx += 256) {
        int i = idx / 36, j = idx - (idx / 36) * 36;
        float acc = 0.f;
        for (int p = 0; p < NP; ++p) acc = fmaf(Dw[i * NP + p], Dw[j * NP + p], acc);
        sM[idx] = acc;
    }
    __syncthreads();

    // normalize by max|.|
    {
        float mx = 0.f;
        for (int idx = tid; idx < 1296; idx += 256) mx = fmaxf(mx, fabsf(sM[idx]));
        sred[tid] = mx;
        __syncthreads();
        for (int s = 128; s > 0; s >>= 1) {
            if (tid < s) sred[tid] = fmaxf(sred[tid], sred[tid + s]);
            __syncthreads();
        }
        float inv = 1.f / sred[0];
        for (int idx = tid; idx < 1296; idx += 256) sB0[idx] = sM[idx] * inv;
    }
    __syncthreads();

    // 8 matrix squarings (M^256 direction), max-normalized each step
    float* bs = sB0;
    float* bd = sB1;
    for (int sq = 0; sq < 8; ++sq) {
        for (int idx = tid; idx < 1296; idx += 256) {
            int i = idx / 36, j = idx - (idx / 36) * 36;
            float acc = 0.f;
            for (int k2 = 0; k2 < 36; ++k2) acc = fmaf(bs[i * 36 + k2], bs[k2 * 36 + j], acc);
            bd[idx] = acc;
        }
        __syncthreads();
        float m2 = 0.f;
        for (int idx = tid; idx < 1296; idx += 256) m2 = fmaxf(m2, fabsf(bd[idx]));
        sred[tid] = m2;
        __syncthreads();
        for (int s = 128; s > 0; s >>= 1) {
            if (tid < s) sred[tid] = fmaxf(sred[tid], sred[tid + s]);
            __syncthreads();
        }
        float inv = 1.f / sred[0];
        for (int idx = tid; idx < 1296; idx += 256) bd[idx] *= inv;
        __syncthreads();
        float* tmp = bs; bs = bd; bd = tmp;
    }

    // v = B·ones; Rayleigh quotient on original M -> L
    if (tid < 36) {
        float s = 0.f;
        for (int k2 = 0; k2 < 36; ++k2) s += bs[tid * 36 + k2];
        sv[tid] = s;
    }
    __syncthreads();
    if (tid < 36) {
        float u = 0.f;
        for (int k2 = 0; k2 < 36; ++k2) u = fmaf(sM[tid * 36 + k2], sv[k2], u);
        sred[tid] = u * sv[tid];
        sred[40 + tid] = sv[tid] * sv[tid];
    }
    __syncthreads();
    if (tid == 0) {
        float num = 0.f, den = 0.f;
        for (int i = 0; i < 36; ++i) { num += sred[i]; den += sred[40 + i]; }
        float L = num / den;
        scal[0] = 1.f / L; scal[1] = L;
    }
}

// ---------------- A = I - DtD/L, padded symmetric [q][p] --------------------
__global__ void k_A(const float* __restrict__ Dw, const float* __restrict__ scal,
                    float* __restrict__ Apad) {
    int idx = blockIdx.x * 256 + threadIdx.x;
    if (idx >= NP * NPAD) return;
    int q = idx / NPAD, p = idx - (idx / NPAD) * NPAD;
    float v = 0.f;
    if (p < NP) {
        float acc = 0.f;
        for (int t = 0; t < TSEQ; ++t) acc = fmaf(Dw[t * NP + q], Dw[t * NP + p], acc);
        v = ((p == q) ? 1.f : 0.f) - acc * scal[0];
    }
    Apad[idx] = v;
}

// ---------------- DtY[n,p,d] = sum_t D[t,p] * Y[n,t,d]  (wide flat) ---------
__global__ void k_dty(const float* __restrict__ Dw, const float* __restrict__ Y,
                      float* __restrict__ dty) {
    int idx = blockIdx.x * 256 + threadIdx.x;
    if (idx >= CSIZE) return;
    int n = idx / NPD;
    int r = idx - n * NPD;
    int p = r / DDATA;
    int d = r - p * DDATA;
    const float* yp = Y + n * TD + d;
    float acc = 0.f;
    for (int t = 0; t < TSEQ; ++t) acc = fmaf(Dw[t * NP + p], yp[t * DDATA], acc);
    dty[idx] = acc;
}

// ---------------- pack A into MFMA fragment order, split bf16 hi/lo ---------
__global__ void k_Afrag(const float* __restrict__ Apad,
                        short* __restrict__ AfH, short* __restrict__ AfL) {
    int idx = blockIdx.x * 256 + threadIdx.x;
    if (idx >= RT_N * KC_N * 64) return;
    int lane = idx & 63;
    int chunk = idx >> 6;
    int kc = chunk % KC_N;
    int rt = chunk / KC_N;
    int p = rt * 16 + (lane & 15);
    int q0 = kc * 32 + (lane >> 4) * 8;
    int base = chunk * FRAG_CHUNK + lane * 8;
#pragma unroll
    for (int j = 0; j < 8; ++j) {
        int q = q0 + j;
        float v = (p < NP && q < NP) ? Apad[q * NPAD + p] : 0.f;  // A[p][q] (symmetric)
        unsigned short h = f2b(v);
        float rem = v - b2f(h);
        AfH[base + j] = (short)h;
        AfL[base + j] = (short)f2b(rem);
    }
}

// ---------------- persistent MFMA FISTA: A in regs, conflict-free y LDS -----
// block=(n, col-quarter dq: 13,13,13,11 cols). grid 512 -> 2 blocks/CU.
// 4 waves: wave w owns row-tiles rt0=w*3 (3,3,3,2), one 16-col tile.
__global__ __launch_bounds__(256, 2) void k_fista(
    const float* __restrict__ Apad,
    const s8b* __restrict__ AfH, const s8b* __restrict__ AfL,
    const float* __restrict__ dty_g, const float* __restrict__ scal,
    const float* __restrict__ ttab, float* __restrict__ Cout)
{
    __shared__ char Yb[2 * YBUF];      // slot*256 + hl*128 + c0*8 (+cur*YBUF)
    __shared__ float yremf[2][16];     // y[row 160][col] f32
    __shared__ float colpart[4][16];
    __shared__ float sS[16];

    const int tid = threadIdx.x;
    const int n  = blockIdx.x >> 2;
    const int dq = blockIdx.x & 3;
    const int w = tid >> 6;
    const int lane = tid & 63;
    const int c0 = lane & 15;
    const int g = lane >> 4;
    const int rt0 = w * 3;
    const int ntr = (w == 3) ? 2 : 3;
    const int ncol = (dq == 3) ? 11 : 13;
    const int colv = dq * 13 + c0;
    const bool cvalid = c0 < ncol;
    const float Linv = scal[0];
    const float lamL = LAMF * Linv;

    const int rdbase = (c0 << 3) + (g << 9);   // c0*8 + g*512
    const int wrbase = (c0 << 3);              // + slot*256 (+128 for lo)

    // ---- persistent A fragments in registers (one-time coalesced load) ----
    s8b ahr[3][KC_N], alr[3][KC_N];
    const s8b zer = {0, 0, 0, 0, 0, 0, 0, 0};
#pragma unroll
    for (int rr = 0; rr < 3; ++rr) {
#pragma unroll
        for (int kc = 0; kc < KC_N; ++kc) {
            if (rr < ntr) {
                int ck = (rt0 + rr) * KC_N + kc;
                ahr[rr][kc] = AfH[ck * 64 + lane];
                alr[rr][kc] = AfL[ck * 64 + lane];
            } else {
                ahr[rr][kc] = zer;
                alr[rr][kc] = zer;
            }
        }
    }

    // tile geometry + dty*Linv + A[:,160] rows (C/D layout: col=l&15, row=g*4+reg)
    int rowb[3];
    float dtL[3][4];
    f4 a160r[3];
#pragma unroll
    for (int rr = 0; rr < 3; ++rr) {
        rowb[rr] = (rt0 + rr) * 16 + g * 4;
#pragma unroll
        for (int r = 0; r < 4; ++r) {
            int row = rowb[rr] + r;
            float v = 0.f;
            if ((rr < ntr) && row < NP && cvalid)
                v = dty_g[n * NPD + row * DDATA + colv];
            dtL[rr][r] = v * Linv;
            a160r[rr][r] = ((rr < ntr) && row < NP) ? Apad[160 * NPAD + row] : 0.f;
        }
    }

    float x_[3][4], wlam_[3][4];
#pragma unroll
    for (int rr = 0; rr < 3; ++rr)
#pragma unroll
        for (int r = 0; r < 4; ++r) wlam_[rr][r] = lamL;

#pragma unroll 1
    for (int round = 0; round < 2; ++round) {
#pragma unroll
        for (int rr = 0; rr < 3; ++rr)
#pragma unroll
            for (int r = 0; r < 4; ++r) x_[rr][r] = 0.f;
        {   // zero read-buffer (index 0); write-buffer fully overwritten at it 0
            unsigned* pz = (unsigned*)Yb;
            for (int i = tid; i < YBUF / 4; i += 256) pz[i] = 0u;
            if (tid < 16) yremf[0][tid] = 0.f;
        }
        int cur = 0;
        __syncthreads();

#pragma unroll 1
        for (int it = 0; it < 100; ++it) {
            const float ttc = ttab[it];          // uniform -> scalar load
            const int nxt = cur ^ 1;
            const char* rp = Yb + cur * YBUF + rdbase;
            char* wp = Yb + nxt * YBUF + wrbase;

            // accumulator initialized with DtY*Linv (folds the bb add)
            f4 acc[3];
#pragma unroll
            for (int rr = 0; rr < 3; ++rr)
#pragma unroll
                for (int r = 0; r < 4; ++r) acc[rr][r] = dtL[rr][r];

            __builtin_amdgcn_s_setprio(1);
#pragma unroll
            for (int kc = 0; kc < KC_N; ++kc) {
                const char* p = rp + kc * 2048;
                u2x2 hh2, ll2;
                hh2.a = *(const uint2*)(p);
                hh2.b = *(const uint2*)(p + 256);
                ll2.a = *(const uint2*)(p + 128);
                ll2.b = *(const uint2*)(p + 384);
                s8b bh = __builtin_bit_cast(s8b, hh2);
                s8b bl = __builtin_bit_cast(s8b, ll2);
#pragma unroll
                for (int rr = 0; rr < 3; ++rr) {
                    if (rr < ntr) {
                        acc[rr] = __builtin_amdgcn_mfma_f32_16x16x32_bf16(ahr[rr][kc], bh, acc[rr], 0, 0, 0);
                        acc[rr] = __builtin_amdgcn_mfma_f32_16x16x32_bf16(ahr[rr][kc], bl, acc[rr], 0, 0, 0);
                        acc[rr] = __builtin_amdgcn_mfma_f32_16x16x32_bf16(alr[rr][kc], bh, acc[rr], 0, 0, 0);
                    }
                }
            }
            {   // q=160 rank-1 term in f32
                float yv = yremf[cur][c0];
#pragma unroll
                for (int rr = 0; rr < 3; ++rr)
                    if (rr < ntr)
#pragma unroll
                        for (int r = 0; r < 4; ++r)
                            acc[rr][r] = fmaf(a160r[rr][r], yv, acc[rr][r]);
            }
            __builtin_amdgcn_s_setprio(0);

            // epilogue: clamp soft-threshold + momentum + truncation-split y
#pragma unroll
            for (int rr = 0; rr < 3; ++rr) {
                if (rr < ntr) {
                    unsigned yb4[4], rb4[4];
                    float yn0 = 0.f;
#pragma unroll
                    for (int r = 0; r < 4; ++r) {
                        float bb = acc[rr][r];
                        float wl = wlam_[rr][r];
                        float cl = fminf(fmaxf(bb, -wl), wl);   // med3 clamp
                        float xn = bb - cl;                      // soft-threshold
                        float yn = fmaf(ttc, xn - x_[rr][r], xn);
                        x_[rr][r] = xn;
                        if (r == 0) yn0 = yn;
                        unsigned u = __float_as_uint(yn);
                        yb4[r] = u;
                        rb4[r] = __float_as_uint(yn - __uint_as_float(u & 0xFFFF0000u));
                    }
                    int rt = rt0 + rr;
                    if (rt < 10) {
                        uint2 hp, lp;
                        hp.x = __builtin_amdgcn_perm(yb4[1], yb4[0], 0x07060302u);
                        hp.y = __builtin_amdgcn_perm(yb4[3], yb4[2], 0x07060302u);
                        lp.x = __builtin_amdgcn_perm(rb4[1], rb4[0], 0x07060302u);
                        lp.y = __builtin_amdgcn_perm(rb4[3], rb4[2], 0x07060302u);
                        char* q = wp + (rt * 4 + g) * 256;
                        *(uint2*)(q)       = hp;
                        *(uint2*)(q + 128) = lp;
                    } else if (g == 0) {
                        yremf[nxt][c0] = yn0;   // row 160 (rows >160 are pad, y=0)
                    }
                }
            }
            __syncthreads();   // writes to nxt visible; all reads of cur complete
            cur = nxt;
        }

        if (round == 0) {
            // reweight: wlam = (1/(|x|+.01)) / colsum(1/(|x|+.01)) * NP * lamL
            float ps = 0.f;
#pragma unroll
            for (int rr = 0; rr < 3; ++rr) {
                if (rr < ntr) {
#pragma unroll
                    for (int r = 0; r < 4; ++r) {
                        if (rowb[rr] + r < NP)
                            ps += 1.f / (fabsf(x_[rr][r]) + 0.01f);
                    }
                }
            }
            ps += __shfl_xor(ps, 16);
            ps += __shfl_xor(ps, 32);
            if (lane < 16) colpart[w][lane] = ps;
            __syncthreads();
            if (tid < 16) {
                float s = colpart[0][tid] + colpart[1][tid] + colpart[2][tid] + colpart[3][tid];
                sS[tid] = (float)NP / s;
            }
            __syncthreads();
            float sc = sS[c0] * lamL;
#pragma unroll
            for (int rr = 0; rr < 3; ++rr)
#pragma unroll
                for (int r = 0; r < 4; ++r)
                    wlam_[rr][r] = (1.f / (fabsf(x_[rr][r]) + 0.01f)) * sc;
            __syncthreads();
        }
    }

    // store C (f32)
#pragma unroll
    for (int rr = 0; rr < 3; ++rr) {
        if ((rr < ntr) && cvalid) {
#pragma unroll
            for (int r = 0; r < 4; ++r) {
                int row = rowb[rr] + r;
                if (row < NP)
                    Cout[n * NPD + row * DDATA + colv] = x_[rr][r];
            }
        }
    }
}

// ---------------- R = D @ C  (wide flat) ------------------------------------
__global__ void k_R(const float* __restrict__ Dw, const float* __restrict__ Cf,
                    float* __restrict__ Rout) {
    int idx = blockIdx.x * 256 + threadIdx.x;
    if (idx >= RSIZE) return;
    int n = idx / TD;
    int r = idx - n * TD;
    int t = r / DDATA;
    int d = r - t * DDATA;
    const float* xp = Cf + n * NPD + d;
    float acc = 0.f;
    for (int p = 0; p < NP; ++p) acc = fmaf(Dw[t * NP + p], xp[p * DDATA], acc);
    Rout[idx] = acc;
}

extern "C" void kernel_launch(void* const* d_in, const int* in_sizes, int n_in,
                              void* d_out, int out_size, void* d_ws, size_t ws_size,
                              hipStream_t stream) {
    const float* Y     = (const float*)d_in[0];
    const float* rho   = (const float*)d_in[1];
    const float* theta = (const float*)d_in[2];
    float* Cout = (float*)d_out;
    float* Dout = Cout + CSIZE;
    float* Rout = Dout + DSIZE;

    float* ws    = (float*)d_ws;
    float* Dw    = ws;                 // 5824
    float* Apad  = Dw + 5824;          // 26416
    float* scal  = Apad + 26416;       // 16
    float* ttabd = scal + 16;          // 112
    float* dty   = ttabd + 112;        // CSIZE
    float* AfH_f = dty + CSIZE;        // 14080 floats (= 28160 shorts)
    float* AfL_f = AfH_f + 14080;      // 14080 floats

    k_build_D<<<(DSIZE + 255) / 256, 256, 0, stream>>>(rho, theta, Dw, Dout);
    k_power2<<<1, 256, 0, stream>>>(Dw, scal, ttabd);
    k_A<<<(NP * NPAD + 255) / 256, 256, 0, stream>>>(Dw, scal, Apad);
    k_dty<<<(CSIZE + 255) / 256, 256, 0, stream>>>(Dw, Y, dty);
    k_Afrag<<<(RT_N * KC_N * 64 + 255) / 256, 256, 0, stream>>>(Apad, (short*)AfH_f, (short*)AfL_f);

    k_fista<<<NSAMP * 4, 256, 0, stream>>>(Apad, (const s8b*)AfH_f, (const s8b*)AfL_f,
                                           dty, scal, ttabd, Cout);

    k_R<<<(RSIZE + 255) / 256, 256, 0, stream>>>(Dw, Cout, Rout);
}

// Round 13
// 370.105 us; speedup vs baseline: 1.0899x; 1.0511x over previous
//
#include <hip/hip_runtime.h>
#include <math.h>

#define NPOLES 80
#define NP 161          // 2*NPOLES+1
#define NPAD 164
#define TSEQ 36
#define NSAMP 128
#define DDATA 50
#define LAMF 0.1f
#define NPD (NP*DDATA)      // 8050
#define TD (TSEQ*DDATA)     // 1800
#define CSIZE (NSAMP*NPD)   // 1030400
#define RSIZE (NSAMP*TD)    // 230400
#define DSIZE (TSEQ*NP)     // 5796

#define RT_N 11             // 176 padded rows / 16
#define KC_N 5              // k chunks of 32 (q=0..159); q=160 via rank-1
#define FRAG_CHUNK 512      // shorts per (rt,kc) fragment: 64 lanes * 8

// y LDS layout: byte = slot*256 + hl*128 + c0*8 ; slot=row/4 (0..39), dbuf stride 10240B
#define YBUF 10240

typedef __attribute__((ext_vector_type(8))) short s8b;
typedef __attribute__((ext_vector_type(4))) float f4;

struct u2x2 { uint2 a, b; };

__device__ __forceinline__ unsigned short f2b(float f) {
    unsigned u = __float_as_uint(f);
    unsigned r = (u + 0x7FFFu + ((u >> 16) & 1u)) >> 16;   // RNE to bf16
    return (unsigned short)r;
}
__device__ __forceinline__ float b2f(unsigned short h) {
    return __uint_as_float(((unsigned)h) << 16);
}

// ---------------- D matrix (clamped poles) ----------------------------------
__global__ void k_build_D(const float* __restrict__ rho, const float* __restrict__ theta,
                          float* __restrict__ Dw, float* __restrict__ Dout) {
    int idx = blockIdx.x * 256 + threadIdx.x;
    if (idx >= DSIZE) return;
    int t = idx / NP, p = idx - (idx / NP) * NP;
    float v;
    if (p == 0) {
        v = 1.f;
    } else {
        int j = (p <= NPOLES) ? (p - 1) : (p - 1 - NPOLES);
        float r  = fminf(fmaxf(rho[j],   0.8f), 1.1f);
        float th = fminf(fmaxf(theta[j], 0.1f), 3.14159265358979323846f);
        double pw  = pow((double)r, (double)t);
        double ang = (double)t * (double)th;
        v = (float)(pw * ((p <= NPOLES) ? cos(ang) : sin(ang)));
    }
    Dw[idx] = v;
    Dout[idx] = v;
}

// ---------------- DDt = D @ D^T  [36x36]  (wide) ----------------------------
__global__ void k_ddt(const float* __restrict__ Dw, float* __restrict__ DDt) {
    int idx = blockIdx.x * 256 + threadIdx.x;
    if (idx >= TSEQ * TSEQ) return;
    int i = idx / TSEQ, j = idx - (idx / TSEQ) * TSEQ;
    float acc = 0.f;
    for (int p = 0; p < NP; ++p) acc = fmaf(Dw[i * NP + p], Dw[j * NP + p], acc);
    DDt[idx] = acc;
}

// -------- parallel L estimator: 8 matrix squarings + Rayleigh (1 block) -----
__global__ __launch_bounds__(256) void k_power2(const float* __restrict__ DDt,
                                                float* __restrict__ scal,
                                                float* __restrict__ ttab) {
    __shared__ float sM[1296];
    __shared__ float sB0[1296];
    __shared__ float sB1[1296];
    __shared__ float sred[256];
    __shared__ float sv[40];
    const int tid = threadIdx.x;

    // momentum table (identical float ops to prior rounds)
    if (tid == 0) {
        float t = 1.f;
        for (int k = 0; k < 100; ++k) {
            float tn = (1.f + sqrtf(fmaf(4.f * t, t, 1.f))) * 0.5f;
            ttab[k] = (t - 1.f) / tn;
            t = tn;
        }
    }

    for (int i = tid; i < 1296; i += 256) sM[i] = DDt[i];
    __syncthreads();

    // normalize by max|.|
    {
        float mx = 0.f;
        for (int idx = tid; idx < 1296; idx += 256) mx = fmaxf(mx, fabsf(sM[idx]));
        sred[tid] = mx;
        __syncthreads();
        for (int s = 128; s > 0; s >>= 1) {
            if (tid < s) sred[tid] = fmaxf(sred[tid], sred[tid + s]);
            __syncthreads();
        }
        float inv = 1.f / sred[0];
        for (int idx = tid; idx < 1296; idx += 256) sB0[idx] = sM[idx] * inv;
    }
    __syncthreads();

    // 8 matrix squarings (M^256 direction), max-normalized each step
    float* bs = sB0;
    float* bd = sB1;
    for (int sq = 0; sq < 8; ++sq) {
        for (int idx = tid; idx < 1296; idx += 256) {
            int i = idx / 36, j = idx - (idx / 36) * 36;
            float acc = 0.f;
            for (int k2 = 0; k2 < 36; ++k2) acc = fmaf(bs[i * 36 + k2], bs[k2 * 36 + j], acc);
            bd[idx] = acc;
        }
        __syncthreads();
        float m2 = 0.f;
        for (int idx = tid; idx < 1296; idx += 256) m2 = fmaxf(m2, fabsf(bd[idx]));
        sred[tid] = m2;
        __syncthreads();
        for (int s = 128; s > 0; s >>= 1) {
            if (tid < s) sred[tid] = fmaxf(sred[tid], sred[tid + s]);
            __syncthreads();
        }
        float inv = 1.f / sred[0];
        for (int idx = tid; idx < 1296; idx += 256) bd[idx] *= inv;
        __syncthreads();
        float* tmp = bs; bs = bd; bd = tmp;
    }

    // v = B·ones; Rayleigh quotient on original M -> L
    if (tid < 36) {
        float s = 0.f;
        for (int k2 = 0; k2 < 36; ++k2) s += bs[tid * 36 + k2];
        sv[tid] = s;
    }
    __syncthreads();
    if (tid < 36) {
        float u = 0.f;
        for (int k2 = 0; k2 < 36; ++k2) u = fmaf(sM[tid * 36 + k2], sv[k2], u);
        sred[tid] = u * sv[tid];
        sred[40 + tid] = sv[tid] * sv[tid];
    }
    __syncthreads();
    if (tid == 0) {
        float num = 0.f, den = 0.f;
        for (int i = 0; i < 36; ++i) { num += sred[i]; den += sred[40 + i]; }
        float L = num / den;
        scal[0] = 1.f / L; scal[1] = L;
    }
}

// ---------------- A = I - DtD/L, padded symmetric [q][p] --------------------
__global__ void k_A(const float* __restrict__ Dw, const float* __restrict__ scal,
                    float* __restrict__ Apad) {
    int idx = blockIdx.x * 256 + threadIdx.x;
    if (idx >= NP * NPAD) return;
    int q = idx / NPAD, p = idx - (idx / NPAD) * NPAD;
    float v = 0.f;
    if (p < NP) {
        float acc = 0.f;
        for (int t = 0; t < TSEQ; ++t) acc = fmaf(Dw[t * NP + q], Dw[t * NP + p], acc);
        v = ((p == q) ? 1.f : 0.f) - acc * scal[0];
    }
    Apad[idx] = v;
}

// ------- DtY, wide flat, x2-vectorized over d (bit-identical fma chains) ----
__global__ void k_dty(const float* __restrict__ Dw, const float* __restrict__ Y,
                      float* __restrict__ dty) {
    int idx = blockIdx.x * 256 + threadIdx.x;          // (n,p,dpair)
    if (idx >= NSAMP * NP * 25) return;
    int n = idx / (NP * 25);
    int r = idx - n * (NP * 25);
    int p = r / 25;
    int dp = r - p * 25;
    const float* yp = Y + n * TD + 2 * dp;
    float a0 = 0.f, a1 = 0.f;
    for (int t = 0; t < TSEQ; ++t) {
        float2 y2 = *reinterpret_cast<const float2*>(yp + t * DDATA);
        float dv = Dw[t * NP + p];
        a0 = fmaf(dv, y2.x, a0);
        a1 = fmaf(dv, y2.y, a1);
    }
    *reinterpret_cast<float2*>(dty + n * NPD + p * DDATA + 2 * dp) = make_float2(a0, a1);
}

// ---------------- pack A into MFMA fragment order, split bf16 hi/lo ---------
__global__ void k_Afrag(const float* __restrict__ Apad,
                        short* __restrict__ AfH, short* __restrict__ AfL) {
    int idx = blockIdx.x * 256 + threadIdx.x;
    if (idx >= RT_N * KC_N * 64) return;
    int lane = idx & 63;
    int chunk = idx >> 6;
    int kc = chunk % KC_N;
    int rt = chunk / KC_N;
    int p = rt * 16 + (lane & 15);
    int q0 = kc * 32 + (lane >> 4) * 8;
    int base = chunk * FRAG_CHUNK + lane * 8;
#pragma unroll
    for (int j = 0; j < 8; ++j) {
        int q = q0 + j;
        float v = (p < NP && q < NP) ? Apad[q * NPAD + p] : 0.f;  // A[p][q] (symmetric)
        unsigned short h = f2b(v);
        float rem = v - b2f(h);
        AfH[base + j] = (short)h;
        AfL[base + j] = (short)f2b(rem);
    }
}

// ---------------- persistent MFMA FISTA: A in regs, conflict-free y LDS -----
// block=(n, col-quarter dq: 13,13,13,11 cols). grid 512 -> 2 blocks/CU.
// 4 waves: wave w owns row-tiles rt0=w*3 (3,3,3,2), one 16-col tile.
__global__ __launch_bounds__(256, 2) void k_fista(
    const float* __restrict__ Apad,
    const s8b* __restrict__ AfH, const s8b* __restrict__ AfL,
    const float* __restrict__ dty_g, const float* __restrict__ scal,
    const float* __restrict__ ttab, float* __restrict__ Cout)
{
    __shared__ char Yb[2 * YBUF];      // slot*256 + hl*128 + c0*8 (+cur*YBUF)
    __shared__ float yremf[2][16];     // y[row 160][col] f32
    __shared__ float colpart[4][16];
    __shared__ float sS[16];

    const int tid = threadIdx.x;
    const int n  = blockIdx.x >> 2;
    const int dq = blockIdx.x & 3;
    const int w = tid >> 6;
    const int lane = tid & 63;
    const int c0 = lane & 15;
    const int g = lane >> 4;
    const int rt0 = w * 3;
    const int ntr = (w == 3) ? 2 : 3;
    const int ncol = (dq == 3) ? 11 : 13;
    const int colv = dq * 13 + c0;
    const bool cvalid = c0 < ncol;
    const float Linv = scal[0];
    const float lamL = LAMF * Linv;

    const int rdbase = (c0 << 3) + (g << 9);   // c0*8 + g*512
    const int wrbase = (c0 << 3);              // + slot*256 (+128 for lo)

    // ---- persistent A fragments in registers (one-time coalesced load) ----
    s8b ahr[3][KC_N], alr[3][KC_N];
    const s8b zer = {0, 0, 0, 0, 0, 0, 0, 0};
#pragma unroll
    for (int rr = 0; rr < 3; ++rr) {
#pragma unroll
        for (int kc = 0; kc < KC_N; ++kc) {
            if (rr < ntr) {
                int ck = (rt0 + rr) * KC_N + kc;
                ahr[rr][kc] = AfH[ck * 64 + lane];
                alr[rr][kc] = AfL[ck * 64 + lane];
            } else {
                ahr[rr][kc] = zer;
                alr[rr][kc] = zer;
            }
        }
    }

    // tile geometry + dty*Linv + A[:,160] rows (C/D layout: col=l&15, row=g*4+reg)
    int rowb[3];
    float dtL[3][4];
    f4 a160r[3];
#pragma unroll
    for (int rr = 0; rr < 3; ++rr) {
        rowb[rr] = (rt0 + rr) * 16 + g * 4;
#pragma unroll
        for (int r = 0; r < 4; ++r) {
            int row = rowb[rr] + r;
            float v = 0.f;
            if ((rr < ntr) && row < NP && cvalid)
                v = dty_g[n * NPD + row * DDATA + colv];
            dtL[rr][r] = v * Linv;
            a160r[rr][r] = ((rr < ntr) && row < NP) ? Apad[160 * NPAD + row] : 0.f;
        }
    }

    float x_[3][4], wlam_[3][4];
#pragma unroll
    for (int rr = 0; rr < 3; ++rr)
#pragma unroll
        for (int r = 0; r < 4; ++r) wlam_[rr][r] = lamL;

#pragma unroll 1
    for (int round = 0; round < 2; ++round) {
#pragma unroll
        for (int rr = 0; rr < 3; ++rr)
#pragma unroll
            for (int r = 0; r < 4; ++r) x_[rr][r] = 0.f;
        {   // zero read-buffer (index 0); write-buffer fully overwritten at it 0
            unsigned* pz = (unsigned*)Yb;
            for (int i = tid; i < YBUF / 4; i += 256) pz[i] = 0u;
            if (tid < 16) yremf[0][tid] = 0.f;
        }
        int cur = 0;
        __syncthreads();

#pragma unroll 1
        for (int it = 0; it < 100; ++it) {
            const float ttc = ttab[it];          // uniform -> scalar load
            const int nxt = cur ^ 1;
            const char* rp = Yb + cur * YBUF + rdbase;
            char* wp = Yb + nxt * YBUF + wrbase;

            // accumulator initialized with DtY*Linv (folds the bb add)
            f4 acc[3];
#pragma unroll
            for (int rr = 0; rr < 3; ++rr)
#pragma unroll
                for (int r = 0; r < 4; ++r) acc[rr][r] = dtL[rr][r];

            __builtin_amdgcn_s_setprio(1);
#pragma unroll
            for (int kc = 0; kc < KC_N; ++kc) {
                const char* p = rp + kc * 2048;
                u2x2 hh2, ll2;
                hh2.a = *(const uint2*)(p);
                hh2.b = *(const uint2*)(p + 256);
                ll2.a = *(const uint2*)(p + 128);
                ll2.b = *(const uint2*)(p + 384);
                s8b bh = __builtin_bit_cast(s8b, hh2);
                s8b bl = __builtin_bit_cast(s8b, ll2);
#pragma unroll
                for (int rr = 0; rr < 3; ++rr) {
                    if (rr < ntr) {
                        acc[rr] = __builtin_amdgcn_mfma_f32_16x16x32_bf16(ahr[rr][kc], bh, acc[rr], 0, 0, 0);
                        acc[rr] = __builtin_amdgcn_mfma_f32_16x16x32_bf16(ahr[rr][kc], bl, acc[rr], 0, 0, 0);
                        acc[rr] = __builtin_amdgcn_mfma_f32_16x16x32_bf16(alr[rr][kc], bh, acc[rr], 0, 0, 0);
                    }
                }
            }
            {   // q=160 rank-1 term in f32
                float yv = yremf[cur][c0];
#pragma unroll
                for (int rr = 0; rr < 3; ++rr)
                    if (rr < ntr)
#pragma unroll
                        for (int r = 0; r < 4; ++r)
                            acc[rr][r] = fmaf(a160r[rr][r], yv, acc[rr][r]);
            }
            __builtin_amdgcn_s_setprio(0);

            // epilogue: clamp soft-threshold + momentum + truncation-split y
#pragma unroll
            for (int rr = 0; rr < 3; ++rr) {
                if (rr < ntr) {
                    unsigned yb4[4], rb4[4];
                    float yn0 = 0.f;
#pragma unroll
                    for (int r = 0; r < 4; ++r) {
                        float bb = acc[rr][r];
                        float wl = wlam_[rr][r];
                        float cl = fminf(fmaxf(bb, -wl), wl);   // med3 clamp
                        float xn = bb - cl;                      // soft-threshold
                        float yn = fmaf(ttc, xn - x_[rr][r], xn);
                        x_[rr][r] = xn;
                        if (r == 0) yn0 = yn;
                        unsigned u = __float_as_uint(yn);
                        yb4[r] = u;
                        rb4[r] = __float_as_uint(yn - __uint_as_float(u & 0xFFFF0000u));
                    }
                    int rt = rt0 + rr;
                    if (rt < 10) {
                        uint2 hp, lp;
                        hp.x = __builtin_amdgcn_perm(yb4[1], yb4[0], 0x07060302u);
                        hp.y = __builtin_amdgcn_perm(yb4[3], yb4[2], 0x07060302u);
                        lp.x = __builtin_amdgcn_perm(rb4[1], rb4[0], 0x07060302u);
                        lp.y = __builtin_amdgcn_perm(rb4[3], rb4[2], 0x07060302u);
                        char* q = wp + (rt * 4 + g) * 256;
                        *(uint2*)(q)       = hp;
                        *(uint2*)(q + 128) = lp;
                    } else if (g == 0) {
                        yremf[nxt][c0] = yn0;   // row 160 (rows >160 are pad, y=0)
                    }
                }
            }
            __syncthreads();   // writes to nxt visible; all reads of cur complete
            cur = nxt;
        }

        if (round == 0) {
            // reweight: wlam = (1/(|x|+.01)) / colsum(1/(|x|+.01)) * NP * lamL
            float ps = 0.f;
#pragma unroll
            for (int rr = 0; rr < 3; ++rr) {
                if (rr < ntr) {
#pragma unroll
                    for (int r = 0; r < 4; ++r) {
                        if (rowb[rr] + r < NP)
                            ps += 1.f / (fabsf(x_[rr][r]) + 0.01f);
                    }
                }
            }
            ps += __shfl_xor(ps, 16);
            ps += __shfl_xor(ps, 32);
            if (lane < 16) colpart[w][lane] = ps;
            __syncthreads();
            if (tid < 16) {
                float s = colpart[0][tid] + colpart[1][tid] + colpart[2][tid] + colpart[3][tid];
                sS[tid] = (float)NP / s;
            }
            __syncthreads();
            float sc = sS[c0] * lamL;
#pragma unroll
            for (int rr = 0; rr < 3; ++rr)
#pragma unroll
                for (int r = 0; r < 4; ++r)
                    wlam_[rr][r] = (1.f / (fabsf(x_[rr][r]) + 0.01f)) * sc;
            __syncthreads();
        }
    }

    // store C (f32)
#pragma unroll
    for (int rr = 0; rr < 3; ++rr) {
        if ((rr < ntr) && cvalid) {
#pragma unroll
            for (int r = 0; r < 4; ++r) {
                int row = rowb[rr] + r;
                if (row < NP)
                    Cout[n * NPD + row * DDATA + colv] = x_[rr][r];
            }
        }
    }
}

// ------- R = D @ C, wide flat, x2-vectorized over d (bit-identical) ---------
__global__ void k_R(const float* __restrict__ Dw, const float* __restrict__ Cf,
                    float* __restrict__ Rout) {
    int idx = blockIdx.x * 256 + threadIdx.x;          // (n,t,dpair)
    if (idx >= NSAMP * TSEQ * 25) return;
    int n = idx / (TSEQ * 25);
    int r = idx - n * (TSEQ * 25);
    int t = r / 25;
    int dp = r - t * 25;
    const float* xp = Cf + n * NPD + 2 * dp;
    float a0 = 0.f, a1 = 0.f;
    for (int p = 0; p < NP; ++p) {
        float2 c2 = *reinterpret_cast<const float2*>(xp + p * DDATA);
        float dv = Dw[t * NP + p];
        a0 = fmaf(dv, c2.x, a0);
        a1 = fmaf(dv, c2.y, a1);
    }
    *reinterpret_cast<float2*>(Rout + n * TD + t * DDATA + 2 * dp) = make_float2(a0, a1);
}

extern "C" void kernel_launch(void* const* d_in, const int* in_sizes, int n_in,
                              void* d_out, int out_size, void* d_ws, size_t ws_size,
                              hipStream_t stream) {
    const float* Y     = (const float*)d_in[0];
    const float* rho   = (const float*)d_in[1];
    const float* theta = (const float*)d_in[2];
    float* Cout = (float*)d_out;
    float* Dout = Cout + CSIZE;
    float* Rout = Dout + DSIZE;

    float* ws    = (float*)d_ws;
    float* Dw    = ws;                 // 5824
    float* Apad  = Dw + 5824;          // 26416
    float* DDt   = Apad + 26416;       // 1312
    float* scal  = DDt + 1312;         // 16
    float* ttabd = scal + 16;          // 112
    float* dty   = ttabd + 112;        // CSIZE
    float* AfH_f = dty + CSIZE;        // 14080 floats (= 28160 shorts)
    float* AfL_f = AfH_f + 14080;      // 14080 floats

    k_build_D<<<(DSIZE + 255) / 256, 256, 0, stream>>>(rho, theta, Dw, Dout);
    k_ddt<<<(TSEQ * TSEQ + 255) / 256, 256, 0, stream>>>(Dw, DDt);
    k_power2<<<1, 256, 0, stream>>>(DDt, scal, ttabd);
    k_A<<<(NP * NPAD + 255) / 256, 256, 0, stream>>>(Dw, scal, Apad);
    k_dty<<<(NSAMP * NP * 25 + 255) / 256, 256, 0, stream>>>(Dw, Y, dty);
    k_Afrag<<<(RT_N * KC_N * 64 + 255) / 256, 256, 0, stream>>>(Apad, (short*)AfH_f, (short*)AfL_f);

    k_fista<<<NSAMP * 4, 256, 0, stream>>>(Apad, (const s8b*)AfH_f, (const s8b*)AfL_f,
                                           dty, scal, ttabd, Cout);

    k_R<<<(NSAMP * TSEQ * 25 + 255) / 256, 256, 0, stream>>>(Dw, Cout, Rout);
}